// Round 9
// baseline (867.104 us; speedup 1.0000x reference)
//
#include <hip/hip_runtime.h>
#include <hip/hip_bf16.h>
#include <float.h>
#include <math.h>

#define K_DIM 768
#define V_DIM 50257
#define PADV  50304              // 393*128 padded vocab
#define M_TOT 4096
#define EMB_N 3145728            // 2*2048*768
#define TAB_N 38597376           // 50257*768
#define NT128 393                // N tiles of 128
#define GSPLIT 32                // N splits for MFMA kernel
#define NCAND 64                 // GSPLIT * top2
#define NSPLIT 16                // fallback fp32 kernel splits
#define NTILES ((V_DIM + 127) / 128)
#define NOISE_BLK (EMB_N / 256)            // 12288
#define BSPLIT_BLK ((PADV * K_DIM / 4) / 256)  // 37728

typedef __attribute__((ext_vector_type(8))) short short8;
typedef __attribute__((ext_vector_type(4))) float f32x4;
typedef unsigned long long u64;

// ---------------- JAX threefry2x32 (key = (0, 42)), 20 rounds ----------------
__device__ __forceinline__ unsigned rotl32(unsigned v, int d) {
  return (v << d) | (v >> (32 - d));
}
__device__ __forceinline__ void threefry2x32_042(unsigned& x0, unsigned& x1) {
  const unsigned ks0 = 0u, ks1 = 42u;
  const unsigned ks2 = ks0 ^ ks1 ^ 0x1BD11BDAu;
  x0 += ks0; x1 += ks1;
#define TF_R(r) { x0 += x1; x1 = rotl32(x1, (r)); x1 ^= x0; }
  TF_R(13) TF_R(15) TF_R(26) TF_R(6)
  x0 += ks1; x1 += ks2 + 1u;
  TF_R(17) TF_R(29) TF_R(16) TF_R(24)
  x0 += ks2; x1 += ks0 + 2u;
  TF_R(13) TF_R(15) TF_R(26) TF_R(6)
  x0 += ks0; x1 += ks1 + 3u;
  TF_R(17) TF_R(29) TF_R(16) TF_R(24)
  x0 += ks1; x1 += ks2 + 4u;
  TF_R(13) TF_R(15) TF_R(26) TF_R(6)
  x0 += ks2; x1 += ks0 + 5u;
#undef TF_R
}

// bits -> uniform(-1+2^-24, 1) -> laplace -> /5  (exact JAX op sequence)
__device__ __forceinline__ float bits_to_noise(unsigned bits) {
  unsigned fb = (bits >> 9) | 0x3F800000u;
  float f = __uint_as_float(fb) - 1.0f;
  const float minv = -0.99999994039535522461f;
  float u = __fadd_rn(__fmul_rn(f, 2.0f), minv);
  u = fmaxf(minv, u);
  float s = (u > 0.0f) ? 1.0f : ((u < 0.0f) ? -1.0f : 0.0f);
  float l = s * log1pf(-fabsf(u));
  return __fdiv_rn(l, 5.0f);
}

__device__ __forceinline__ float bf2f(unsigned short b) {
  return __uint_as_float(((unsigned)b) << 16);
}
__device__ __forceinline__ unsigned short f2bf(float x) {
  __hip_bfloat16 h = __float2bfloat16(x);   // RNE
  return *(unsigned short*)&h;
}

// monotone u32 key of float (order-preserving)
__device__ __forceinline__ unsigned fkey(float v) {
  unsigned b = __float_as_uint(v);
  return b ^ (((unsigned)((int)b >> 31)) | 0x80000000u);
}
// u64 (value,index) pack for exact paths
__device__ __forceinline__ u64 pack_maxidx(float v, unsigned idx) {
  return ((u64)fkey(v) << 32) | (u64)(0xFFFFFFFFu - idx);
}
__device__ __forceinline__ unsigned umax32(unsigned a, unsigned b) { return a > b ? a : b; }
__device__ __forceinline__ u64 umax64(u64 a, u64 b) { return a > b ? a : b; }

__device__ __forceinline__ void gload16(const void* g, void* l) {
  __builtin_amdgcn_global_load_lds(
      (const __attribute__((address_space(1))) unsigned*)g,
      (__attribute__((address_space(3))) unsigned*)l, 16, 0, 0);
}

// ============================ FAST PATH ====================================

// fused prep: noisy(f32)->d_out + Ah bf16; table -> Bh bf16 (padded zeroed)
__global__ void prep_kernel(const float* __restrict__ in,
                            const float* __restrict__ tab,
                            float* __restrict__ noisy,
                            unsigned short* __restrict__ Ah,
                            unsigned short* __restrict__ Bh) {
  if (blockIdx.x < NOISE_BLK) {
    const unsigned i = blockIdx.x * 256 + threadIdx.x;
    unsigned x0 = 0u, x1 = i;
    threefry2x32_042(x0, x1);
    float v = in[i] + bits_to_noise(x0 ^ x1);
    noisy[i] = v;
    Ah[i] = f2bf(v);
  } else {
    const size_t i = ((size_t)(blockIdx.x - NOISE_BLK) * 256 + threadIdx.x) * 4;
    ushort4 h;
    if (i < (size_t)TAB_N) {
      float4 v = *(const float4*)(tab + i);
      h.x = f2bf(v.x); h.y = f2bf(v.y); h.z = f2bf(v.z); h.w = f2bf(v.w);
    } else {
      h = make_ushort4(0, 0, 0, 0);
    }
    *(ushort4*)(Bh + i) = h;
  }
}

// bf16 MFMA GEMM (BK=64) with deferred per-thread top-2 (u32 packed).
// LDS: 128 rows x 128B, 16B-slot p swizzled p = q ^ (row&7); staged linearly
// via global_load_lds with pre-swizzled global source (both-sides rule).
__global__ __launch_bounds__(256) void mfma_cand_kernel(
    const unsigned short* __restrict__ Ah,
    const unsigned short* __restrict__ Bh,
    unsigned* __restrict__ cand) {
  __shared__ alignas(16) char ldsA[16384];
  __shared__ alignas(16) char ldsB[16384];
  __shared__ unsigned topscr[128][2][2];

  const int tid = threadIdx.x, lane = tid & 63, w = tid >> 6;
  const int fr = lane & 15, g = lane >> 4;
  const int wr = (w >> 1) * 64, wc = (w & 1) * 64;
  const int bm = blockIdx.x, split = blockIdx.y;

  // staging descriptors: 4 issues per operand per K-step
  int srow[4], scol[4], soff[4];
#pragma unroll
  for (int i = 0; i < 4; ++i) {
    int s = i * 256 + w * 64 + lane;        // LDS 16B-slot index 0..1023
    int row = s >> 3, p = s & 7;
    srow[i] = row;
    scol[i] = (p ^ (row & 7)) * 8;          // source element offset (bf16)
    soff[i] = i * 4096 + w * 1024;          // wave-uniform LDS byte base
  }

  // deferred per-thread top-2 per (m,j): u32 = key[31:11] | (2047-local11)
  unsigned r1[4][4], r2[4][4];
#pragma unroll
  for (int m = 0; m < 4; ++m)
#pragma unroll
    for (int j = 0; j < 4; ++j) { r1[m][j] = 0u; r2[m][j] = 0u; }

  int tidx = 0;   // tile counter within split (0..12)
  for (int t = split; t < NT128; t += GSPLIT, ++tidx) {
    f32x4 acc[4][4];
#pragma unroll
    for (int m = 0; m < 4; ++m)
#pragma unroll
      for (int n = 0; n < 4; ++n) acc[m][n] = (f32x4){0.f, 0.f, 0.f, 0.f};

    const size_t abase = (size_t)bm * 128 * K_DIM;
    const size_t bbase = (size_t)t * 128 * K_DIM;

    for (int ks = 0; ks < K_DIM / 64; ++ks) {
      const int k0 = ks * 64;
      __syncthreads();
#pragma unroll
      for (int i = 0; i < 4; ++i) {
        gload16(Ah + abase + (size_t)srow[i] * K_DIM + k0 + scol[i], ldsA + soff[i]);
        gload16(Bh + bbase + (size_t)srow[i] * K_DIM + k0 + scol[i], ldsB + soff[i]);
      }
      __syncthreads();

      short8 af[4][2], bf[4][2];
#pragma unroll
      for (int m = 0; m < 4; ++m) {
        const int row = wr + m * 16 + fr;
#pragma unroll
        for (int k2 = 0; k2 < 2; ++k2) {
          const int p = (k2 * 4 + g) ^ (row & 7);
          af[m][k2] = *(const short8*)(ldsA + row * 128 + p * 16);
        }
      }
#pragma unroll
      for (int n = 0; n < 4; ++n) {
        const int row = wc + n * 16 + fr;
#pragma unroll
        for (int k2 = 0; k2 < 2; ++k2) {
          const int p = (k2 * 4 + g) ^ (row & 7);
          bf[n][k2] = *(const short8*)(ldsB + row * 128 + p * 16);
        }
      }
#pragma unroll
      for (int m = 0; m < 4; ++m)
#pragma unroll
        for (int n = 0; n < 4; ++n) {
          acc[m][n] = __builtin_amdgcn_mfma_f32_16x16x32_bf16(af[m][0], bf[n][0], acc[m][n], 0, 0, 0);
          acc[m][n] = __builtin_amdgcn_mfma_f32_16x16x32_bf16(af[m][1], bf[n][1], acc[m][n], 0, 0, 0);
        }
    }

    // fold this tile into running per-thread top-2 (no cross-lane work here)
    // local11 = tidx*128 + (wc + n*16 + fr); low field = 2047 - local11
#pragma unroll
    for (int n = 0; n < 4; ++n) {
      const unsigned lowf = 2047u - (unsigned)(tidx * 128 + wc + n * 16 + fr);
#pragma unroll
      for (int m = 0; m < 4; ++m)
#pragma unroll
        for (int j = 0; j < 4; ++j) {
          unsigned pk = (fkey(acc[m][n][j]) & 0xFFFFF800u) | lowf;
          unsigned o1 = r1[m][j];
          r2[m][j] = (pk > o1) ? umax32(r2[m][j] < o1 ? o1 : r2[m][j], 0u) | (pk > o1 ? o1 : 0u)
                               : r2[m][j];  // placeholder, replaced below
          // branch-free top-2 fold:
          unsigned nr1 = umax32(o1, pk);
          unsigned nr2 = (pk > o1) ? o1 : umax32(r2[m][j], pk);
          r1[m][j] = nr1;
          r2[m][j] = nr2;
        }
    }
  }

  // cross-lane (fr) merge of top-2 sets, once per kernel
#pragma unroll
  for (int m = 0; m < 4; ++m)
#pragma unroll
    for (int j = 0; j < 4; ++j) {
      unsigned t1 = r1[m][j], t2 = r2[m][j];
#pragma unroll
      for (int msk = 1; msk < 16; msk <<= 1) {
        unsigned o1 = (unsigned)__shfl_xor((int)t1, msk, 64);
        unsigned o2 = (unsigned)__shfl_xor((int)t2, msk, 64);
        if (o1 > t1) { t2 = umax32(t1, o2); t1 = o1; }
        else t2 = umax32(t2, o1);
      }
      if (fr == 0) {
        int rl = wr + m * 16 + g * 4 + j;
        topscr[rl][w & 1][0] = t1;
        topscr[rl][w & 1][1] = t2;
      }
    }
  __syncthreads();

  if (tid < 128) {
    unsigned a1 = topscr[tid][0][0], a2 = topscr[tid][0][1];
    unsigned b1 = topscr[tid][1][0], b2 = topscr[tid][1][1];
    unsigned m1, m2;
    if (a1 > b1) { m1 = a1; m2 = umax32(a2, b1); }
    else         { m1 = b1; m2 = umax32(b2, a1); }
    // decode cols
    unsigned l1 = 2047u - (m1 & 0x7FFu);
    unsigned l2 = 2047u - (m2 & 0x7FFu);
    unsigned c1 = (unsigned)((split + (l1 >> 7) * GSPLIT) * 128) + (l1 & 127u);
    unsigned c2 = (unsigned)((split + (l2 >> 7) * GSPLIT) * 128) + (l2 & 127u);
    if (c1 >= V_DIM) c1 = 0;
    if (c2 >= V_DIM) c2 = 0;
    int grow = bm * 128 + tid;
    cand[(grow * GSPLIT + split) * 2 + 0] = c1;
    cand[(grow * GSPLIT + split) * 2 + 1] = c2;
  }
}

// exact fp32 rescore of 64 candidates/row
__global__ void rescore_kernel(const float* __restrict__ noisy,
                               const float* __restrict__ table,
                               const unsigned* __restrict__ cand,
                               u64* __restrict__ merged) {
  const int row = blockIdx.x;
  const int lane = threadIdx.x;   // 64
  const unsigned ci = cand[row * NCAND + lane];
  const float* a = noisy + (size_t)row * K_DIM;
  const float* b = table + (size_t)ci * K_DIM;
  float s = 0.f;
  for (int k = 0; k < K_DIM; ++k) s = fmaf(a[k], b[k], s);
  u64 p = pack_maxidx(s, ci);
#pragma unroll
  for (int m = 1; m < 64; m <<= 1) {
    u64 o = (u64)__shfl_xor((long long)p, m, 64);
    if (o > p) p = o;
  }
  if (lane == 0) merged[row] = p;
}

// ============================ FALLBACK (verified round-6) ===================

__global__ void noise_add_kernel(const float* __restrict__ in,
                                 float* __restrict__ noisy,
                                 u64* __restrict__ merged) {
  const unsigned i = blockIdx.x * blockDim.x + threadIdx.x;
  if (i >= EMB_N) return;
  if (i < M_TOT) merged[i] = 0ull;
  unsigned x0 = 0u, x1 = i;
  threefry2x32_042(x0, x1);
  noisy[i] = in[i] + bits_to_noise(x0 ^ x1);
}

__global__ __launch_bounds__(256) void gemm_argmax_kernel(
    const float* __restrict__ noisy, const float* __restrict__ table,
    u64* __restrict__ merged) {
  __shared__ float As[16][132];
  __shared__ float Bs[16][132];
  __shared__ float redm[128][16];
  __shared__ int   redi[128][16];

  const int tid = threadIdx.x;
  const int lane = tid & 63;
  const int w = tid >> 6;
  const int tx = lane & 7, ty = lane >> 3;
  const int col0 = (w & 1) * 64 + tx * 8;
  const int row0 = (w >> 1) * 64 + ty * 8;
  const int bm = blockIdx.x;
  const int split = blockIdx.y;
  const float* Abase = noisy + (size_t)bm * 128 * K_DIM;

  float rmax[8]; int ridx[8];
#pragma unroll
  for (int r = 0; r < 8; ++r) { rmax[r] = -INFINITY; ridx[r] = 0x7FFFFFFF; }

  for (int t = split; t < NTILES; t += NSPLIT) {
    const int nbase = t * 128;
    float acc[8][8];
#pragma unroll
    for (int r = 0; r < 8; ++r)
#pragma unroll
      for (int c = 0; c < 8; ++c) acc[r][c] = 0.0f;

    for (int k0 = 0; k0 < K_DIM; k0 += 16) {
      __syncthreads();
#pragma unroll
      for (int l = 0; l < 2; ++l) {
        const int e = tid + l * 256;
        const int ml = e >> 2, kk = (e & 3) << 2;
        float4 av = *(const float4*)(Abase + (size_t)ml * K_DIM + k0 + kk);
        As[kk + 0][ml] = av.x; As[kk + 1][ml] = av.y;
        As[kk + 2][ml] = av.z; As[kk + 3][ml] = av.w;
        const int n = nbase + ml;
        float4 bv = make_float4(0.f, 0.f, 0.f, 0.f);
        if (n < V_DIM)
          bv = *(const float4*)(table + (size_t)n * K_DIM + k0 + kk);
        Bs[kk + 0][ml] = bv.x; Bs[kk + 1][ml] = bv.y;
        Bs[kk + 2][ml] = bv.z; Bs[kk + 3][ml] = bv.w;
      }
      __syncthreads();
#pragma unroll
      for (int k = 0; k < 16; ++k) {
        float4 a0 = *(const float4*)&As[k][row0];
        float4 a1 = *(const float4*)&As[k][row0 + 4];
        float4 b0 = *(const float4*)&Bs[k][col0];
        float4 b1 = *(const float4*)&Bs[k][col0 + 4];
        float a[8] = {a0.x, a0.y, a0.z, a0.w, a1.x, a1.y, a1.z, a1.w};
        float b[8] = {b0.x, b0.y, b0.z, b0.w, b1.x, b1.y, b1.z, b1.w};
#pragma unroll
        for (int r = 0; r < 8; ++r)
#pragma unroll
          for (int c = 0; c < 8; ++c)
            acc[r][c] = fmaf(a[r], b[c], acc[r][c]);
      }
    }
#pragma unroll
    for (int r = 0; r < 8; ++r)
#pragma unroll
      for (int c = 0; c < 8; ++c) {
        const int n = nbase + col0 + c;
        if (n < V_DIM && acc[r][c] > rmax[r]) { rmax[r] = acc[r][c]; ridx[r] = n; }
      }
  }

  __syncthreads();
#pragma unroll
  for (int r = 0; r < 8; ++r) {
    redm[row0 + r][(w & 1) * 8 + tx] = rmax[r];
    redi[row0 + r][(w & 1) * 8 + tx] = ridx[r];
  }
  __syncthreads();
  if (tid < 128) {
    float best = -INFINITY; int bi = 0x7FFFFFFF;
#pragma unroll
    for (int j = 0; j < 16; ++j) {
      float v = redm[tid][j]; int id = redi[tid][j];
      if (v > best || (v == best && id < bi)) { best = v; bi = id; }
    }
    atomicMax(&merged[bm * 128 + tid], pack_maxidx(best, (unsigned)bi));
  }
}

// ---------------- shared: unpack index + gather table row -------------------
__global__ void gather_kernel(const u64* __restrict__ merged,
                              const float* __restrict__ table,
                              float* __restrict__ out) {
  const int row = blockIdx.x;
  const int tid = threadIdx.x;
  const unsigned bi = 0xFFFFFFFFu - (unsigned)(merged[row] & 0xFFFFFFFFull);
  if (tid < 192) {
    float4 val = *(const float4*)(table + (size_t)bi * K_DIM + tid * 4);
    *(float4*)(out + (size_t)row * K_DIM + tid * 4) = val;
  }
}

// ---------------- launch ----------------
extern "C" void kernel_launch(void* const* d_in, const int* in_sizes, int n_in,
                              void* d_out, int out_size, void* d_ws, size_t ws_size,
                              hipStream_t stream) {
  const float* inputs = (const float*)d_in[0];
  const float* table  = (const float*)d_in[1];
  if (n_in >= 2 && (in_sizes[0] == TAB_N || in_sizes[1] == EMB_N)) {
    table  = (const float*)d_in[0];
    inputs = (const float*)d_in[1];
  }
  float* out = (float*)d_out;
  float* noisy = out;   // overwritten by gather at the end

  // fast-path ws layout (bytes)
  const size_t oAh = 0;
  const size_t oBh = oAh + (size_t)EMB_N * 2;            //  6,291,456
  const size_t oCand = oBh + (size_t)PADV * K_DIM * 2;   // 83,558,400
  const size_t oMerged = oCand + (size_t)M_TOT * NCAND * 4;
  const size_t REQ = oMerged + (size_t)M_TOT * 8;        // ~84.6 MB

  if (ws_size >= REQ) {
    unsigned short* Ah = (unsigned short*)((char*)d_ws + oAh);
    unsigned short* Bh = (unsigned short*)((char*)d_ws + oBh);
    unsigned* cand = (unsigned*)((char*)d_ws + oCand);
    u64* merged = (u64*)((char*)d_ws + oMerged);

    prep_kernel<<<NOISE_BLK + BSPLIT_BLK, 256, 0, stream>>>(inputs, table, noisy, Ah, Bh);
    dim3 g2(M_TOT / 128, GSPLIT);
    mfma_cand_kernel<<<g2, 256, 0, stream>>>(Ah, Bh, cand);
    rescore_kernel<<<M_TOT, 64, 0, stream>>>(noisy, table, cand, merged);
    gather_kernel<<<M_TOT, 256, 0, stream>>>(merged, table, out);
  } else {
    u64* merged = (u64*)d_ws;
    noise_add_kernel<<<EMB_N / 256, 256, 0, stream>>>(inputs, noisy, merged);
    dim3 g2(M_TOT / 128, NSPLIT);
    gemm_argmax_kernel<<<g2, 256, 0, stream>>>(noisy, table, merged);
    gather_kernel<<<M_TOT, 256, 0, stream>>>(merged, table, out);
  }
}

// Round 10
// 624.677 us; speedup vs baseline: 1.3881x; 1.3881x over previous
//
#include <hip/hip_runtime.h>
#include <hip/hip_bf16.h>
#include <float.h>
#include <math.h>

#define K_DIM 768
#define V_DIM 50257
#define PADV  50304              // 393*128 padded vocab
#define M_TOT 4096
#define EMB_N 3145728            // 2*2048*768
#define TAB_N 38597376           // 50257*768
#define NT128 393                // N tiles of 128
#define GSPLIT 32                // N splits for MFMA kernel
#define NCAND 64                 // GSPLIT * top2
#define NSPLIT 16                // fallback fp32 kernel splits
#define NTILES ((V_DIM + 127) / 128)
#define NOISE_BLK (EMB_N / 256)                // 12288
#define BSPLIT_BLK ((PADV * K_DIM / 4) / 256)  // 37728

typedef __attribute__((ext_vector_type(8))) short short8;
typedef __attribute__((ext_vector_type(4))) float f32x4;
typedef unsigned long long u64;

// ---------------- JAX threefry2x32 (key = (0, 42)), 20 rounds ----------------
__device__ __forceinline__ unsigned rotl32(unsigned v, int d) {
  return (v << d) | (v >> (32 - d));
}
__device__ __forceinline__ void threefry2x32_042(unsigned& x0, unsigned& x1) {
  const unsigned ks0 = 0u, ks1 = 42u;
  const unsigned ks2 = ks0 ^ ks1 ^ 0x1BD11BDAu;
  x0 += ks0; x1 += ks1;
#define TF_R(r) { x0 += x1; x1 = rotl32(x1, (r)); x1 ^= x0; }
  TF_R(13) TF_R(15) TF_R(26) TF_R(6)
  x0 += ks1; x1 += ks2 + 1u;
  TF_R(17) TF_R(29) TF_R(16) TF_R(24)
  x0 += ks2; x1 += ks0 + 2u;
  TF_R(13) TF_R(15) TF_R(26) TF_R(6)
  x0 += ks0; x1 += ks1 + 3u;
  TF_R(17) TF_R(29) TF_R(16) TF_R(24)
  x0 += ks1; x1 += ks2 + 4u;
  TF_R(13) TF_R(15) TF_R(26) TF_R(6)
  x0 += ks2; x1 += ks0 + 5u;
#undef TF_R
}

// bits -> uniform(-1+2^-24, 1) -> laplace -> /5  (exact JAX op sequence)
__device__ __forceinline__ float bits_to_noise(unsigned bits) {
  unsigned fb = (bits >> 9) | 0x3F800000u;
  float f = __uint_as_float(fb) - 1.0f;
  const float minv = -0.99999994039535522461f;
  float u = __fadd_rn(__fmul_rn(f, 2.0f), minv);
  u = fmaxf(minv, u);
  float s = (u > 0.0f) ? 1.0f : ((u < 0.0f) ? -1.0f : 0.0f);
  float l = s * log1pf(-fabsf(u));
  return __fdiv_rn(l, 5.0f);
}

__device__ __forceinline__ float bf2f(unsigned short b) {
  return __uint_as_float(((unsigned)b) << 16);
}
__device__ __forceinline__ unsigned short f2bf(float x) {
  __hip_bfloat16 h = __float2bfloat16(x);   // RNE
  return *(unsigned short*)&h;
}

// monotone u32 key of float (order-preserving)
__device__ __forceinline__ unsigned fkey(float v) {
  unsigned b = __float_as_uint(v);
  return b ^ (((unsigned)((int)b >> 31)) | 0x80000000u);
}
// u64 (value,index) pack for exact paths
__device__ __forceinline__ u64 pack_maxidx(float v, unsigned idx) {
  return ((u64)fkey(v) << 32) | (u64)(0xFFFFFFFFu - idx);
}
__device__ __forceinline__ unsigned umax32(unsigned a, unsigned b) { return a > b ? a : b; }
__device__ __forceinline__ unsigned umin32(unsigned a, unsigned b) { return a < b ? a : b; }

__device__ __forceinline__ void gload16(const void* g, void* l) {
  __builtin_amdgcn_global_load_lds(
      (const __attribute__((address_space(1))) unsigned*)g,
      (__attribute__((address_space(3))) unsigned*)l, 16, 0, 0);
}

// ============================ FAST PATH ====================================

// fused prep: noisy(f32)->d_out + Ah bf16; table -> Bh bf16 (padded zeroed)
__global__ void prep_kernel(const float* __restrict__ in,
                            const float* __restrict__ tab,
                            float* __restrict__ noisy,
                            unsigned short* __restrict__ Ah,
                            unsigned short* __restrict__ Bh) {
  if (blockIdx.x < NOISE_BLK) {
    const unsigned i = blockIdx.x * 256 + threadIdx.x;
    unsigned x0 = 0u, x1 = i;
    threefry2x32_042(x0, x1);
    float v = in[i] + bits_to_noise(x0 ^ x1);
    noisy[i] = v;
    Ah[i] = f2bf(v);
  } else {
    const size_t i = ((size_t)(blockIdx.x - NOISE_BLK) * 256 + threadIdx.x) * 4;
    ushort4 h;
    if (i < (size_t)TAB_N) {
      float4 v = *(const float4*)(tab + i);
      h.x = f2bf(v.x); h.y = f2bf(v.y); h.z = f2bf(v.z); h.w = f2bf(v.w);
    } else {
      h = make_ushort4(0, 0, 0, 0);
    }
    *(ushort4*)(Bh + i) = h;
  }
}

// bf16 MFMA GEMM (BK=64), per-tile top-2 reduction with u32 packed keys.
// key = fkey(score)[31:11] | (2047 - local11), local11 = tidx*128 + col_in_tile.
// LDS: 128 rows x 128B, 16B-slot p swizzled p = q ^ (row&7); staged linearly
// via global_load_lds with pre-swizzled global source (both-sides rule).
__global__ __launch_bounds__(256) void mfma_cand_kernel(
    const unsigned short* __restrict__ Ah,
    const unsigned short* __restrict__ Bh,
    unsigned* __restrict__ cand) {
  __shared__ alignas(16) char ldsA[16384];
  __shared__ alignas(16) char ldsB[16384];
  __shared__ unsigned topscr[128][2][2];

  const int tid = threadIdx.x, lane = tid & 63, w = tid >> 6;
  const int fr = lane & 15, g = lane >> 4;
  const int wr = (w >> 1) * 64, wc = (w & 1) * 64;
  const int bm = blockIdx.x, split = blockIdx.y;

  // staging descriptors: 4 issues per operand per K-step
  int srow[4], scol[4], soff[4];
#pragma unroll
  for (int i = 0; i < 4; ++i) {
    int s = i * 256 + w * 64 + lane;        // LDS 16B-slot index 0..1023
    int row = s >> 3, p = s & 7;
    srow[i] = row;
    scol[i] = (p ^ (row & 7)) * 8;          // source element offset (bf16)
    soff[i] = i * 4096 + w * 1024;          // wave-uniform LDS byte base
  }

  unsigned run1 = 0u, run2 = 0u;   // running per-row top-2 (tid<128 only)

  int tidx = 0;   // tile counter within split (0..12)
  for (int t = split; t < NT128; t += GSPLIT, ++tidx) {
    f32x4 acc[4][4];
#pragma unroll
    for (int m = 0; m < 4; ++m)
#pragma unroll
      for (int n = 0; n < 4; ++n) acc[m][n] = (f32x4){0.f, 0.f, 0.f, 0.f};

    const size_t abase = (size_t)bm * 128 * K_DIM;
    const size_t bbase = (size_t)t * 128 * K_DIM;

    for (int ks = 0; ks < K_DIM / 64; ++ks) {
      const int k0 = ks * 64;
      __syncthreads();
#pragma unroll
      for (int i = 0; i < 4; ++i) {
        gload16(Ah + abase + (size_t)srow[i] * K_DIM + k0 + scol[i], ldsA + soff[i]);
        gload16(Bh + bbase + (size_t)srow[i] * K_DIM + k0 + scol[i], ldsB + soff[i]);
      }
      __syncthreads();

      short8 af[4][2], bf[4][2];
#pragma unroll
      for (int m = 0; m < 4; ++m) {
        const int row = wr + m * 16 + fr;
#pragma unroll
        for (int k2 = 0; k2 < 2; ++k2) {
          const int p = (k2 * 4 + g) ^ (row & 7);
          af[m][k2] = *(const short8*)(ldsA + row * 128 + p * 16);
        }
      }
#pragma unroll
      for (int n = 0; n < 4; ++n) {
        const int row = wc + n * 16 + fr;
#pragma unroll
        for (int k2 = 0; k2 < 2; ++k2) {
          const int p = (k2 * 4 + g) ^ (row & 7);
          bf[n][k2] = *(const short8*)(ldsB + row * 128 + p * 16);
        }
      }
#pragma unroll
      for (int m = 0; m < 4; ++m)
#pragma unroll
        for (int n = 0; n < 4; ++n) {
          acc[m][n] = __builtin_amdgcn_mfma_f32_16x16x32_bf16(af[m][0], bf[n][0], acc[m][n], 0, 0, 0);
          acc[m][n] = __builtin_amdgcn_mfma_f32_16x16x32_bf16(af[m][1], bf[n][1], acc[m][n], 0, 0, 0);
        }
    }

    // per-tile top-2 per row, u32 keys; C/D: col=lane&15, row=g*4+j
    unsigned lowf[4];
#pragma unroll
    for (int n = 0; n < 4; ++n)
      lowf[n] = 2047u - (unsigned)(tidx * 128 + wc + n * 16 + fr);

#pragma unroll
    for (int m = 0; m < 4; ++m)
#pragma unroll
      for (int j = 0; j < 4; ++j) {
        // pack 4 columns
        unsigned p0 = (fkey(acc[m][0][j]) & 0xFFFFF800u) | lowf[0];
        unsigned p1 = (fkey(acc[m][1][j]) & 0xFFFFF800u) | lowf[1];
        unsigned p2 = (fkey(acc[m][2][j]) & 0xFFFFF800u) | lowf[2];
        unsigned p3 = (fkey(acc[m][3][j]) & 0xFFFFF800u) | lowf[3];
        // sort-network top-2 of 4
        unsigned a1 = umax32(p0, p1), a2 = umin32(p0, p1);
        unsigned b1 = umax32(p2, p3), b2 = umin32(p2, p3);
        unsigned t1 = umax32(a1, b1);
        unsigned t2 = umax32(umin32(a1, b1), umax32(a2, b2));
        // butterfly over fr (16 lanes)
#pragma unroll
        for (int msk = 1; msk < 16; msk <<= 1) {
          unsigned o1 = (unsigned)__shfl_xor((int)t1, msk, 64);
          unsigned o2 = (unsigned)__shfl_xor((int)t2, msk, 64);
          if (o1 > t1) { t2 = umax32(t1, o2); t1 = o1; }
          else t2 = umax32(t2, o1);
        }
        if (fr == 0) {
          int rl = wr + m * 16 + g * 4 + j;
          topscr[rl][w & 1][0] = t1;
          topscr[rl][w & 1][1] = t2;
        }
      }
    __syncthreads();
    if (tid < 128) {
      unsigned a1 = topscr[tid][0][0], a2 = topscr[tid][0][1];
      unsigned b1 = topscr[tid][1][0], b2 = topscr[tid][1][1];
      unsigned m1, m2;
      if (a1 > b1) { m1 = a1; m2 = umax32(a2, b1); }
      else         { m1 = b1; m2 = umax32(b2, a1); }
      if (m1 > run1) { run2 = umax32(run1, m2); run1 = m1; }
      else run2 = umax32(run2, m1);
    }
  }

  if (tid < 128) {
    unsigned l1 = 2047u - (run1 & 0x7FFu);
    unsigned l2 = 2047u - (run2 & 0x7FFu);
    unsigned c1 = (unsigned)((split + (l1 >> 7) * GSPLIT) * 128) + (l1 & 127u);
    unsigned c2 = (unsigned)((split + (l2 >> 7) * GSPLIT) * 128) + (l2 & 127u);
    if (c1 >= V_DIM) c1 = 0;
    if (c2 >= V_DIM) c2 = 0;
    int grow = bm * 128 + tid;
    cand[(grow * GSPLIT + split) * 2 + 0] = c1;
    cand[(grow * GSPLIT + split) * 2 + 1] = c2;
  }
}

// exact fp32 rescore of 64 candidates/row
__global__ void rescore_kernel(const float* __restrict__ noisy,
                               const float* __restrict__ table,
                               const unsigned* __restrict__ cand,
                               u64* __restrict__ merged) {
  const int row = blockIdx.x;
  const int lane = threadIdx.x;   // 64
  const unsigned ci = cand[row * NCAND + lane];
  const float* a = noisy + (size_t)row * K_DIM;
  const float* b = table + (size_t)ci * K_DIM;
  float s = 0.f;
  for (int k = 0; k < K_DIM; ++k) s = fmaf(a[k], b[k], s);
  u64 p = pack_maxidx(s, ci);
#pragma unroll
  for (int m = 1; m < 64; m <<= 1) {
    u64 o = (u64)__shfl_xor((long long)p, m, 64);
    if (o > p) p = o;
  }
  if (lane == 0) merged[row] = p;
}

// ============================ FALLBACK (verified round-6) ===================

__global__ void noise_add_kernel(const float* __restrict__ in,
                                 float* __restrict__ noisy,
                                 u64* __restrict__ merged) {
  const unsigned i = blockIdx.x * blockDim.x + threadIdx.x;
  if (i >= EMB_N) return;
  if (i < M_TOT) merged[i] = 0ull;
  unsigned x0 = 0u, x1 = i;
  threefry2x32_042(x0, x1);
  noisy[i] = in[i] + bits_to_noise(x0 ^ x1);
}

__global__ __launch_bounds__(256) void gemm_argmax_kernel(
    const float* __restrict__ noisy, const float* __restrict__ table,
    u64* __restrict__ merged) {
  __shared__ float As[16][132];
  __shared__ float Bs[16][132];
  __shared__ float redm[128][16];
  __shared__ int   redi[128][16];

  const int tid = threadIdx.x;
  const int lane = tid & 63;
  const int w = tid >> 6;
  const int tx = lane & 7, ty = lane >> 3;
  const int col0 = (w & 1) * 64 + tx * 8;
  const int row0 = (w >> 1) * 64 + ty * 8;
  const int bm = blockIdx.x;
  const int split = blockIdx.y;
  const float* Abase = noisy + (size_t)bm * 128 * K_DIM;

  float rmax[8]; int ridx[8];
#pragma unroll
  for (int r = 0; r < 8; ++r) { rmax[r] = -INFINITY; ridx[r] = 0x7FFFFFFF; }

  for (int t = split; t < NTILES; t += NSPLIT) {
    const int nbase = t * 128;
    float acc[8][8];
#pragma unroll
    for (int r = 0; r < 8; ++r)
#pragma unroll
      for (int c = 0; c < 8; ++c) acc[r][c] = 0.0f;

    for (int k0 = 0; k0 < K_DIM; k0 += 16) {
      __syncthreads();
#pragma unroll
      for (int l = 0; l < 2; ++l) {
        const int e = tid + l * 256;
        const int ml = e >> 2, kk = (e & 3) << 2;
        float4 av = *(const float4*)(Abase + (size_t)ml * K_DIM + k0 + kk);
        As[kk + 0][ml] = av.x; As[kk + 1][ml] = av.y;
        As[kk + 2][ml] = av.z; As[kk + 3][ml] = av.w;
        const int n = nbase + ml;
        float4 bv = make_float4(0.f, 0.f, 0.f, 0.f);
        if (n < V_DIM)
          bv = *(const float4*)(table + (size_t)n * K_DIM + k0 + kk);
        Bs[kk + 0][ml] = bv.x; Bs[kk + 1][ml] = bv.y;
        Bs[kk + 2][ml] = bv.z; Bs[kk + 3][ml] = bv.w;
      }
      __syncthreads();
#pragma unroll
      for (int k = 0; k < 16; ++k) {
        float4 a0 = *(const float4*)&As[k][row0];
        float4 a1 = *(const float4*)&As[k][row0 + 4];
        float4 b0 = *(const float4*)&Bs[k][col0];
        float4 b1 = *(const float4*)&Bs[k][col0 + 4];
        float a[8] = {a0.x, a0.y, a0.z, a0.w, a1.x, a1.y, a1.z, a1.w};
        float b[8] = {b0.x, b0.y, b0.z, b0.w, b1.x, b1.y, b1.z, b1.w};
#pragma unroll
        for (int r = 0; r < 8; ++r)
#pragma unroll
          for (int c = 0; c < 8; ++c)
            acc[r][c] = fmaf(a[r], b[c], acc[r][c]);
      }
    }
#pragma unroll
    for (int r = 0; r < 8; ++r)
#pragma unroll
      for (int c = 0; c < 8; ++c) {
        const int n = nbase + col0 + c;
        if (n < V_DIM && acc[r][c] > rmax[r]) { rmax[r] = acc[r][c]; ridx[r] = n; }
      }
  }

  __syncthreads();
#pragma unroll
  for (int r = 0; r < 8; ++r) {
    redm[row0 + r][(w & 1) * 8 + tx] = rmax[r];
    redi[row0 + r][(w & 1) * 8 + tx] = ridx[r];
  }
  __syncthreads();
  if (tid < 128) {
    float best = -INFINITY; int bi = 0x7FFFFFFF;
#pragma unroll
    for (int j = 0; j < 16; ++j) {
      float v = redm[tid][j]; int id = redi[tid][j];
      if (v > best || (v == best && id < bi)) { best = v; bi = id; }
    }
    atomicMax(&merged[bm * 128 + tid], pack_maxidx(best, (unsigned)bi));
  }
}

// ---------------- shared: unpack index + gather table row -------------------
__global__ void gather_kernel(const u64* __restrict__ merged,
                              const float* __restrict__ table,
                              float* __restrict__ out) {
  const int row = blockIdx.x;
  const int tid = threadIdx.x;
  const unsigned bi = 0xFFFFFFFFu - (unsigned)(merged[row] & 0xFFFFFFFFull);
  if (tid < 192) {
    float4 val = *(const float4*)(table + (size_t)bi * K_DIM + tid * 4);
    *(float4*)(out + (size_t)row * K_DIM + tid * 4) = val;
  }
}

// ---------------- launch ----------------
extern "C" void kernel_launch(void* const* d_in, const int* in_sizes, int n_in,
                              void* d_out, int out_size, void* d_ws, size_t ws_size,
                              hipStream_t stream) {
  const float* inputs = (const float*)d_in[0];
  const float* table  = (const float*)d_in[1];
  if (n_in >= 2 && (in_sizes[0] == TAB_N || in_sizes[1] == EMB_N)) {
    table  = (const float*)d_in[0];
    inputs = (const float*)d_in[1];
  }
  float* out = (float*)d_out;
  float* noisy = out;   // overwritten by gather at the end

  // fast-path ws layout (bytes)
  const size_t oAh = 0;
  const size_t oBh = oAh + (size_t)EMB_N * 2;            //  6,291,456
  const size_t oCand = oBh + (size_t)PADV * K_DIM * 2;   // 83,558,400
  const size_t oMerged = oCand + (size_t)M_TOT * NCAND * 4;
  const size_t REQ = oMerged + (size_t)M_TOT * 8;        // ~84.6 MB

  if (ws_size >= REQ) {
    unsigned short* Ah = (unsigned short*)((char*)d_ws + oAh);
    unsigned short* Bh = (unsigned short*)((char*)d_ws + oBh);
    unsigned* cand = (unsigned*)((char*)d_ws + oCand);
    u64* merged = (u64*)((char*)d_ws + oMerged);

    prep_kernel<<<NOISE_BLK + BSPLIT_BLK, 256, 0, stream>>>(inputs, table, noisy, Ah, Bh);
    dim3 g2(M_TOT / 128, GSPLIT);
    mfma_cand_kernel<<<g2, 256, 0, stream>>>(Ah, Bh, cand);
    rescore_kernel<<<M_TOT, 64, 0, stream>>>(noisy, table, cand, merged);
    gather_kernel<<<M_TOT, 256, 0, stream>>>(merged, table, out);
  } else {
    u64* merged = (u64*)d_ws;
    noise_add_kernel<<<EMB_N / 256, 256, 0, stream>>>(inputs, noisy, merged);
    dim3 g2(M_TOT / 128, NSPLIT);
    gemm_argmax_kernel<<<g2, 256, 0, stream>>>(noisy, table, merged);
    gather_kernel<<<M_TOT, 256, 0, stream>>>(merged, table, out);
  }
}